// Round 9
// baseline (988.046 us; speedup 1.0000x reference)
//
#include <hip/hip_runtime.h>
#include <cstdint>
#include <cstddef>

#define DEV __device__ __forceinline__

typedef unsigned int uint32;
typedef unsigned short ushort16;
typedef __bf16 bfx8 __attribute__((ext_vector_type(8)));
typedef float f32x4 __attribute__((ext_vector_type(4)));

constexpr int D = 128;
constexpr int CAP = 64;               // max in-degree per list (Poisson(16): P(>64)~1e-20)
constexpr float MINN  = 1e-15f;
constexpr float MAXN  = 1.0f - 4e-3f; // (1 - BALL_EPS)/sqrt(c), c=1
constexpr float ACLIP = 1.0f - 1e-7f;

DEV float wave_sum(float v) {
#pragma unroll
  for (int off = 32; off > 0; off >>= 1) v += __shfl_xor(v, off, 64);
  return v;
}

DEV float artanh_clip(float x) {   // x >= 0 in all our uses
  x = fminf(x, ACLIP);
  return 0.5f * logf((1.0f + x) / (1.0f - x));
}

DEV uint32 f2b(float f) {          // fp32 -> bf16 RNE (low 16 bits)
  uint32 u = __float_as_uint(f);
  u += 0x7fffu + ((u >> 16) & 1u);
  return u >> 16;
}
DEV float b2f_lo(uint32 v) { return __uint_as_float(v << 16); }
DEV float b2f_hi(uint32 v) { return __uint_as_float(v & 0xffff0000u); }

// ---------------------------------------------------------------- bucket build
// Direct fixed-capacity bucket fill, XCD-partitioned (block%8 -> dst range),
// both edge lists in one dispatch (y = list). No hist/scan needed.
__global__ __launch_bounds__(256) void fillc_k(
    const int* __restrict__ sp, const int* __restrict__ dp,
    const int* __restrict__ sn, const int* __restrict__ dn, int E,
    int* __restrict__ cp, int* __restrict__ cn,
    int* __restrict__ lp, int* __restrict__ ln, int rngsz, int chunkE) {
  const int* __restrict__ src = blockIdx.y ? sn : sp;
  const int* __restrict__ dst = blockIdx.y ? dn : dp;
  int* __restrict__ cur = blockIdx.y ? cn : cp;
  int* __restrict__ lst = blockIdx.y ? ln : lp;
  const int r = blockIdx.x & 7;
  const int chunk = blockIdx.x >> 3;
  const unsigned lo = (unsigned)(r * rngsz);
  const int base = chunk * chunkE;
  const int end = min(base + chunkE, E);
  for (int i = base + (int)threadIdx.x; i < end; i += 256) {
    int d = dst[i];
    if ((unsigned)d - lo < (unsigned)rngsz) {
      int p = atomicAdd(&cur[d], 1);
      if (p < CAP) lst[(size_t)d * CAP + p] = src[i];
    }
  }
}

// ---------------------------------------------------------------- constants
// x -> xsq (rowsumsq) + bf16 copy + fp32 copy into d_out[:,256:384] + zero cur arrays
__global__ void rowsq_k(const float* __restrict__ x, float* __restrict__ xsq,
                        ushort16* __restrict__ xb, float* __restrict__ outx,
                        int* __restrict__ curz, int nz, int n) {
  int gid = blockIdx.x * 256 + (int)threadIdx.x;
  if (gid < nz) curz[gid] = 0;
  int lane = threadIdx.x & 63;
  int row = blockIdx.x * 4 + (threadIdx.x >> 6);
  if (row >= n) return;
  const float2 v = *(const float2*)(x + (size_t)row * D + lane * 2);
  uint32 pk = f2b(v.x) | (f2b(v.y) << 16);
  *(uint32*)(xb + (size_t)row * D + lane * 2) = pk;
  *(float2*)(outx + (size_t)row * 384 + 256 + lane * 2) = v;
  float s = wave_sum(v.x * v.x + v.y * v.y);
  if (lane == 0) xsq[row] = s;
}

// all six hyperbolic biases in one dispatch; block i handles bias i
struct BiasDesc { const float* b[6]; float* hb[6]; int dim[6]; };
__global__ void bias_all_k(BiasDesc bd, float* __restrict__ hbsq) {
  int i = blockIdx.x;
  int lane = threadIdx.x;
  const float* b = bd.b[i];
  float* hb = bd.hb[i];
  int ne = bd.dim[i] / 64;
  float v[4];
  float ssq = 0.0f;
  for (int e = 0; e < ne; ++e) { v[e] = b[e * 64 + lane]; ssq += v[e] * v[e]; }
  ssq = wave_sum(ssq);
  float nr = sqrtf(ssq);
  float nc = fmaxf(nr, MINN);
  float es = tanhf(nc) / nc;
  float on = es * nr;
  float f = (on > MAXN) ? (MAXN / fmaxf(on, MINN)) : 1.0f;
  float w = es * f;
  float osq = 0.0f;
  for (int e = 0; e < ne; ++e) { v[e] *= w; osq += v[e] * v[e]; hb[e * 64 + lane] = v[e]; }
  osq = wave_sum(osq);
  if (lane == 0) hbsq[i] = osq;
}

// W [DOUT,K] fp32 row-major -> bf16 MFMA-B fragment order:
// frag f = jt*(K/32)+kc; lane l holds B[col=jt*16+(l&15)][k=kc*32+(l>>4)*8 .. +7]
struct WsDesc { const float* src[6]; ushort16* dst[6]; int K[6]; int total[6]; };
__global__ void wshuf_all_k(WsDesc wd) {
  int y = blockIdx.y;
  int tid = blockIdx.x * 256 + threadIdx.x;
  if (tid >= wd.total[y]) return;
  int K = wd.K[y];
  int l = tid & 63;
  int fc = tid >> 6;
  int nkc = K / 32;
  int kc = fc % nkc;
  int jt = fc / nkc;
  int col = jt * 16 + (l & 15);
  int kb = kc * 32 + (l >> 4) * 8;
  const float* src = wd.src[y] + (size_t)col * K + kb;
  uint32 o[4];
#pragma unroll
  for (int m = 0; m < 4; ++m) o[m] = f2b(src[2 * m]) | (f2b(src[2 * m + 1]) << 16);
  *(uint4*)(wd.dst[y] + (size_t)tid * 8) = make_uint4(o[0], o[1], o[2], o[3]);
}

// ---------------------------------------------------------------- aggregation
// mean over fixed-capacity bucket; latency-bound -> maximize waves x in-flight.
// NF=2: block = 4 waves = 2 rows x 2 halves; each wave gathers its 256B half
//       (64 lanes x u32, 8-deep unroll) independently (separate mean/norm).
// NF=1: block = 4 waves = 2 rows x 2 edge-parities; LDS combine of partials.
struct AggJob {
  const char* T;                      // table base
  const int* cnt; const int* lst;
  ushort16* OutLo; ushort16* OutHi;   // 128-col bf16 rows
  float* Slo; float* Shi;
};

template <int NF>
__global__ __launch_bounds__(256) void agg2_k(AggJob ja, AggJob jbv, int n) {
  AggJob jb = blockIdx.y ? jbv : ja;
  const int l = threadIdx.x & 63;
  const int wv = (int)threadIdx.x >> 6;
  const int row = blockIdx.x * 2 + (wv >> 1);
  const int half = wv & 1;
  if (NF == 2) {
    if (row >= n) return;
    const int cnt = jb.cnt[row];
    const int m = min(cnt, CAP);
    const int* __restrict__ lst = jb.lst + (size_t)row * CAP;
    const char* __restrict__ T = jb.T + half * 256 + l * 4;
    float a0 = 0, a1 = 0;
    int j = 0;
    for (; j + 7 < m; j += 8) {
      uint32 v[8];
#pragma unroll
      for (int q = 0; q < 8; ++q) v[q] = *(const uint32*)(T + (size_t)lst[j + q] * 512);
#pragma unroll
      for (int q = 0; q < 8; ++q) { a0 += b2f_lo(v[q]); a1 += b2f_hi(v[q]); }
    }
    for (; j < m; ++j) {
      uint32 v = *(const uint32*)(T + (size_t)lst[j] * 512);
      a0 += b2f_lo(v); a1 += b2f_hi(v);
    }
    float inv = 1.0f / fmaxf((float)cnt, 1.0f);
    a0 *= inv; a1 *= inv;
    float sq = wave_sum(a0 * a0 + a1 * a1);
    ushort16* Out = half ? jb.OutHi : jb.OutLo;
    *(uint32*)((char*)Out + (size_t)row * 256 + l * 4) = f2b(a0) | (f2b(a1) << 16);
    if (l == 0) (half ? jb.Shi : jb.Slo)[row] = sq;
  } else {
    __shared__ float2 part[2][64];
    const bool valid = row < n;
    int cnt = 0, m = 0;
    const int* __restrict__ lst = nullptr;
    if (valid) { cnt = jb.cnt[row]; m = min(cnt, CAP); lst = jb.lst + (size_t)row * CAP; }
    const char* __restrict__ T = jb.T + l * 4;
    float a0 = 0, a1 = 0;
    if (valid) {
      int j = half;
      for (; j + 14 < m; j += 16) {   // 8 edges of this parity
        uint32 v[8];
#pragma unroll
        for (int q = 0; q < 8; ++q) v[q] = *(const uint32*)(T + (size_t)lst[j + 2 * q] * 256);
#pragma unroll
        for (int q = 0; q < 8; ++q) { a0 += b2f_lo(v[q]); a1 += b2f_hi(v[q]); }
      }
      for (; j < m; j += 2) {
        uint32 v = *(const uint32*)(T + (size_t)lst[j] * 256);
        a0 += b2f_lo(v); a1 += b2f_hi(v);
      }
    }
    if (half) part[wv >> 1][l] = make_float2(a0, a1);
    __syncthreads();
    if (!valid || half) return;
    float2 p = part[wv >> 1][l];
    a0 += p.x; a1 += p.y;
    float inv = 1.0f / fmaxf((float)cnt, 1.0f);
    a0 *= inv; a1 *= inv;
    float sq = wave_sum(a0 * a0 + a1 * a1);
    *(uint32*)((char*)jb.OutLo + (size_t)row * 256 + l * 4) = f2b(a0) | (f2b(a1) << 16);
    if (l == 0) jb.Slo[row] = sq;
  }
}

// ------------------------------------------------ bf16 MFMA GEMM + hyperbolic epilogue
// Two independent jobs per dispatch (blockIdx.y). Block: 64 rows x full dout.
// A = NC chunks of 128 k, register-prefetched; B direct from pre-shuffled W.
// bf16 output routed per 128-col group (ob0/ob1) so outputs may alias the
// row-aligned A-input tables (WAR-safe within a block; rows disjoint across blocks).
struct GJob {
  const ushort16* p[3];
  int lda[3], ko[3];
  const ushort16* Wp;
  const float *xs0, *xs1, *xs2;
  const float *hb, *hbsq_p;
  ushort16 *ob0, *ob1; int ldob;
  float* outf; int ldof, ocol;
  float* hsq_out;
};

template <int NC, int NCT>   // NCT: 2 -> dout=128, 4 -> dout=256
__global__ __launch_bounds__(256) void gemm3_k(GJob j0, GJob j1, int M) {
  GJob jb = blockIdx.y ? j1 : j0;
  __shared__ char As[16384];                 // [64 rows][128 k] bf16, XOR-swizzled
  __shared__ float hbs[NCT * 64];
  __shared__ float redA[4][64][2];
  __shared__ float redB[4][64];
  __shared__ float rs[64][4];
  const int t = threadIdx.x;
  const int l = t & 63;
  const int w = t >> 6;
  const int brow = blockIdx.x * 64;
  constexpr int KC32 = NC * 4;
  const int srow = t >> 4;
  const int sco = t & 15;

  for (int c = t; c < NCT * 64; c += 256) hbs[c] = jb.hb[c];

  auto gaddr = [&](int c, int h) -> const uint4* {
    int gr = min(brow + srow + h * 16, M - 1);   // clamp stays inside this block's rows
    return (const uint4*)(jb.p[c] + jb.ko[c] + (size_t)gr * jb.lda[c] + sco * 8);
  };

  f32x4 acc[4][NCT] = {};
  uint4 rga[4];
#pragma unroll
  for (int h = 0; h < 4; ++h) rga[h] = *gaddr(0, h);

#pragma unroll
  for (int c = 0; c < NC; ++c) {
#pragma unroll
    for (int h = 0; h < 4; ++h) {
      int row = srow + h * 16;
      *(uint4*)(As + row * 256 + ((sco * 16) ^ ((row & 7) << 4))) = rga[h];
    }
    __syncthreads();
    if (c + 1 < NC) {
#pragma unroll
      for (int h = 0; h < 4; ++h) rga[h] = *gaddr(c + 1, h);   // in flight during MFMA
    }
#pragma unroll
    for (int ks = 0; ks < 4; ++ks) {
      const int kb = ks * 64 + (l >> 4) * 16;
      bfx8 a[4], b[NCT];
#pragma unroll
      for (int j = 0; j < NCT; ++j)
        b[j] = *(const bfx8*)(jb.Wp + ((size_t)((w * NCT + j) * KC32 + c * 4 + ks)) * 512 + l * 8);
#pragma unroll
      for (int i = 0; i < 4; ++i) {
        int row = i * 16 + (l & 15);
        a[i] = *(const bfx8*)(As + row * 256 + (kb ^ ((row & 7) << 4)));
      }
#pragma unroll
      for (int i = 0; i < 4; ++i)
#pragma unroll
        for (int j = 0; j < NCT; ++j)
          acc[i][j] = __builtin_amdgcn_mfma_f32_16x16x32_bf16(a[i], b[j], acc[i][j], 0, 0, 0);
    }
    __syncthreads();
  }

  // ---- round A: per-row (||mx||^2, <mx,hb>) ----
#pragma unroll
  for (int i = 0; i < 4; ++i)
#pragma unroll
    for (int r = 0; r < 4; ++r) {
      float s = 0.0f, xy = 0.0f;
#pragma unroll
      for (int j = 0; j < NCT; ++j) {
        float m = acc[i][j][r];
        int col = w * (NCT * 16) + j * 16 + (l & 15);
        s += m * m;
        xy += m * hbs[col];
      }
#pragma unroll
      for (int off = 1; off < 16; off <<= 1) {
        s += __shfl_xor(s, off, 64);
        xy += __shfl_xor(xy, off, 64);
      }
      if ((l & 15) == 0) {
        int row = i * 16 + (l >> 4) * 4 + r;
        redA[w][row][0] = s;
        redA[w][row][1] = xy;
      }
    }
  __syncthreads();

  // ---- scalar phase 1 ----
  if (t < 64 && brow + t < M) {
    float ssq = redA[0][t][0] + redA[1][t][0] + redA[2][t][0] + redA[3][t][0];
    float xyr = redA[0][t][1] + redA[1][t][1] + redA[2][t][1] + redA[3][t][1];
    float mxn_raw = sqrtf(ssq);
    float xnsq = jb.xs0[brow + t];
    if (jb.xs1) xnsq += jb.xs1[brow + t];
    if (jb.xs2) xnsq += jb.xs2[brow + t];
    float xn = fmaxf(sqrtf(xnsq), MINN);
    float mxn = fmaxf(mxn_raw, MINN);
    float scal = tanhf(mxn / xn * artanh_clip(xn)) / mxn;
    float rn_raw = scal * mxn_raw;
    if (rn_raw > MAXN) { scal *= MAXN / fmaxf(rn_raw, MINN); rn_raw = MAXN; }
    float xyv = scal * xyr;
    float x2 = rn_raw * rn_raw;
    float y2 = *jb.hbsq_p;
    float den = fmaxf(1.0f + 2.0f * xyv + x2 * y2, MINN);
    float ax = (1.0f + 2.0f * xyv + y2) / den;
    float ay = (1.0f - x2) / den;
    float vsq = scal * scal * ssq;
    float psq = fmaxf(ax * ax * vsq + 2.0f * ax * ay * xyv + ay * ay * y2, 0.0f);
    float pn_raw = sqrtf(psq);
    float f2s = (pn_raw > MAXN) ? (MAXN / fmaxf(pn_raw, MINN)) : 1.0f;
    pn_raw = fminf(pn_raw, MAXN);
    float pn = fmaxf(pn_raw, MINN);
    float la = artanh_clip(pn) / pn * f2s;
    rs[t][0] = scal * ax;
    rs[t][1] = ay;
    rs[t][2] = la;
  }
  __syncthreads();

  // ---- round B: p = c1*mx + c2*hb; ppos = sum(relu(p)^2) ----
#pragma unroll
  for (int i = 0; i < 4; ++i)
#pragma unroll
    for (int r = 0; r < 4; ++r) {
      int row = i * 16 + (l >> 4) * 4 + r;
      float c1 = rs[row][0], c2 = rs[row][1];
      float pp = 0.0f;
#pragma unroll
      for (int j = 0; j < NCT; ++j) {
        int col = w * (NCT * 16) + j * 16 + (l & 15);
        float p = c1 * acc[i][j][r] + c2 * hbs[col];
        p = fmaxf(p, 0.0f);
        acc[i][j][r] = p;
        pp += p * p;
      }
#pragma unroll
      for (int off = 1; off < 16; off <<= 1) pp += __shfl_xor(pp, off, 64);
      if ((l & 15) == 0) redB[w][row] = pp;
    }
  __syncthreads();

  // ---- scalar phase 2 ----
  if (t < 64 && brow + t < M) {
    float ppos = redB[0][t] + redB[1][t] + redB[2][t] + redB[3][t];
    float la = rs[t][2];
    float tsq = la * la * ppos;
    float tn_raw = sqrtf(tsq);
    float tnc = fmaxf(tn_raw, MINN);
    float es = tanhf(tnc) / tnc;
    float on_raw = es * tn_raw;
    float f3 = (on_raw > MAXN) ? (MAXN / fmaxf(on_raw, MINN)) : 1.0f;
    float wsc = es * f3;
    float g = wsc * la;
    rs[t][3] = g;
    if (jb.hsq_out) jb.hsq_out[brow + t] = g * g * ppos;
  }
  __syncthreads();

  // ---- write out = g * relu(p) ----
#pragma unroll
  for (int i = 0; i < 4; ++i)
#pragma unroll
    for (int r = 0; r < 4; ++r) {
      int row = i * 16 + (l >> 4) * 4 + r;
      int gr = brow + row;
      if (gr < M) {
        float g = rs[row][3];
#pragma unroll
        for (int j = 0; j < NCT; ++j) {
          int col = w * (NCT * 16) + j * 16 + (l & 15);
          float o = g * acc[i][j][r];
          if (jb.ob0) {
            ushort16* ob = (col < 128) ? jb.ob0 : jb.ob1;
            ob[(size_t)gr * jb.ldob + (col & 127)] = (ushort16)f2b(o);
          } else {
            jb.outf[(size_t)gr * jb.ldof + jb.ocol + col] = o;
          }
        }
      }
    }
}

// ---------------------------------------------------------------- launcher
extern "C" void kernel_launch(void* const* d_in, const int* in_sizes, int n_in,
                              void* d_out, int out_size, void* d_ws, size_t ws_size,
                              hipStream_t stream) {
  const float* x = (const float*)d_in[0];
  const int* src_pos = (const int*)d_in[1];
  const int* dst_pos = (const int*)d_in[2];
  const int* src_neg = (const int*)d_in[3];
  const int* dst_neg = (const int*)d_in[4];
  const float* W1b = (const float*)d_in[5];
  const float* b1b = (const float*)d_in[6];
  const float* W1h = (const float*)d_in[7];
  const float* b1h = (const float*)d_in[8];
  const float* W2b = (const float*)d_in[9];
  const float* b2b = (const float*)d_in[10];
  const float* W2h = (const float*)d_in[11];
  const float* b2h = (const float*)d_in[12];
  const float* W3b = (const float*)d_in[13];
  const float* b3b = (const float*)d_in[14];
  const float* W3h = (const float*)d_in[15];
  const float* b3h = (const float*)d_in[16];

  const int N = in_sizes[0] / D;   // 100000
  const int E = in_sizes[1];       // 1600000

  // ---- workspace: ints | fp32 | bf16 ----
  int* iw = (int*)d_ws;
  size_t io = 0;
  int* cur_p = iw + io;  io += N;
  int* cur_n = iw + io;  io += N;
  int* lst_p = iw + io;  io += (size_t)N * CAP;
  int* lst_n = iw + io;  io += (size_t)N * CAP;
  io = (io + 63) & ~(size_t)63;

  float* fw = (float*)(iw + io);
  size_t fo = 0;
  float* xsq = fw + fo;    fo += N;
  float* hsq_b1 = fw + fo; fo += N;
  float* hsq_n1 = fw + fo; fo += N;
  float* hsq_b2 = fw + fo; fo += N;
  float* hsq_n2 = fw + fo; fo += N;
  float* ssq_p1 = fw + fo; fo += N;
  float* ssq_n1 = fw + fo; fo += N;
  float* ssq_pp = fw + fo; fo += N;   // ||A_P(hb1)||^2
  float* ssq_np = fw + fo; fo += N;   // ||A_P(hn1)||^2
  float* ssq_nn = fw + fo; fo += N;   // ||A_N(hn1)||^2
  float* ssq_bn = fw + fo; fo += N;   // ||A_N(hb1)||^2
  float* hbase = fw + fo;  fo += 1056;
  fo = (fo + 31) & ~(size_t)31;

  ushort16* SB = (ushort16*)(fw + fo);
  const size_t NSB = (size_t)N * D;
  ushort16* TA = SB;             // xb          -> A_N(hn1) -> HB2 hi
  ushort16* H1 = SB + NSB;       // [N,256] hb1|hn1 interleaved (2 slots)
  ushort16* TD = SB + 3 * NSB;   // A_P(x)  -> A_P(hb1) -> HB2 lo
  ushort16* TE = SB + 4 * NSB;   // A_N(x)  -> A_P(hn1) -> HN2 lo
  ushort16* TF = SB + 5 * NSB;   //            A_N(hb1) -> HN2 hi
  ushort16* wb1b = SB + 6 * NSB;
  ushort16* wb1h = wb1b + 32768;
  ushort16* wb2b = wb1h + 32768;
  ushort16* wb2h = wb2b + 98304;
  ushort16* wb3b = wb2h + 98304;
  ushort16* wb3h = wb3b + 32768;

  float* outf = (float*)d_out;

  float* hb1b = hbase + 0;
  float* hb1h = hbase + 128;
  float* hb2b = hbase + 256;
  float* hb2h = hbase + 512;
  float* hb3b = hbase + 768;
  float* hb3h = hbase + 896;
  float* hbsq = hbase + 1024;

  const int grow = (N + 3) / 4;
  const int grow2 = (N + 1) / 2;
  const int gf = (N + 63) / 64;
  const int rngsz = (N + 7) / 8;
  const int chunkE = (E + 255) / 256;
  const int gpart = 256 * 8;

  // ---- constants + cur zeroing (rowsq precedes fillc) ----
  rowsq_k<<<grow, 256, 0, stream>>>(x, xsq, TA, outf, cur_p, 2 * N, N);
  fillc_k<<<dim3(gpart, 2), 256, 0, stream>>>(src_pos, dst_pos, src_neg, dst_neg, E,
                                              cur_p, cur_n, lst_p, lst_n, rngsz, chunkE);
  {
    BiasDesc bd;
    bd.b[0] = b1b; bd.hb[0] = hb1b; bd.dim[0] = 128;
    bd.b[1] = b1h; bd.hb[1] = hb1h; bd.dim[1] = 128;
    bd.b[2] = b2b; bd.hb[2] = hb2b; bd.dim[2] = 256;
    bd.b[3] = b2h; bd.hb[3] = hb2h; bd.dim[3] = 256;
    bd.b[4] = b3b; bd.hb[4] = hb3b; bd.dim[4] = 128;
    bd.b[5] = b3h; bd.hb[5] = hb3h; bd.dim[5] = 128;
    bias_all_k<<<6, 64, 0, stream>>>(bd, hbsq);
  }
  {
    WsDesc wd;
    wd.src[0] = W1b; wd.dst[0] = wb1b; wd.K[0] = 256; wd.total[0] = 8 * 8 * 64;
    wd.src[1] = W1h; wd.dst[1] = wb1h; wd.K[1] = 256; wd.total[1] = 8 * 8 * 64;
    wd.src[2] = W2b; wd.dst[2] = wb2b; wd.K[2] = 384; wd.total[2] = 16 * 12 * 64;
    wd.src[3] = W2h; wd.dst[3] = wb2h; wd.K[3] = 384; wd.total[3] = 16 * 12 * 64;
    wd.src[4] = W3b; wd.dst[4] = wb3b; wd.K[4] = 256; wd.total[4] = 8 * 8 * 64;
    wd.src[5] = W3h; wd.dst[5] = wb3h; wd.K[5] = 256; wd.total[5] = 8 * 8 * 64;
    wshuf_all_k<<<dim3(48, 6), 256, 0, stream>>>(wd);
  }

  // ---- layer 1 aggs: A_P(x)->TD, A_N(x)->TE ----
  {
    AggJob jp{(const char*)TA, cur_p, lst_p, TD, nullptr, ssq_p1, nullptr};
    AggJob jn{(const char*)TA, cur_n, lst_n, TE, nullptr, ssq_n1, nullptr};
    agg2_k<1><<<dim3(grow2, 2), 256, 0, stream>>>(jp, jn, N);
  }
  // ---- layer 1 gemms: write hb1|hn1 interleaved into H1 ----
  {
    GJob ja{}, jh{};
    ja.p[0] = TD; ja.lda[0] = 128; ja.ko[0] = 0;
    ja.p[1] = TA; ja.lda[1] = 128; ja.ko[1] = 0;
    ja.Wp = wb1b; ja.xs0 = ssq_p1; ja.xs1 = xsq; ja.xs2 = nullptr;
    ja.hb = hb1b; ja.hbsq_p = hbsq + 0;
    ja.ob0 = H1; ja.ob1 = nullptr; ja.ldob = 256;
    ja.outf = nullptr; ja.ldof = 0; ja.ocol = 0; ja.hsq_out = hsq_b1;
    jh = ja;
    jh.p[0] = TE; jh.Wp = wb1h; jh.xs0 = ssq_n1;
    jh.hb = hb1h; jh.hbsq_p = hbsq + 1; jh.ob0 = H1 + 128; jh.hsq_out = hsq_n1;
    gemm3_k<2, 2><<<dim3(gf, 2), 256, 0, stream>>>(ja, jh, N);
  }

  // ---- layer 2 aggs over interleaved H1 (lo half = hb1, hi half = hn1) ----
  {
    // P job: OutLo = A_P(hb1)=TD, OutHi = A_P(hn1)=TE
    AggJob jp{(const char*)H1, cur_p, lst_p, TD, TE, ssq_pp, ssq_np};
    // N job: OutLo = A_N(hb1)=TF, OutHi = A_N(hn1)=TA
    AggJob jn{(const char*)H1, cur_n, lst_n, TF, TA, ssq_bn, ssq_nn};
    agg2_k<2><<<dim3(grow2, 2), 256, 0, stream>>>(jp, jn, N);
  }
  // ---- layer 2 gemms: HB2 -> [TD|TA], HN2 -> [TE|TF] (alias inputs, row-aligned) ----
  {
    GJob ja{}, jh{};
    ja.p[0] = TD; ja.lda[0] = 128; ja.ko[0] = 0;
    ja.p[1] = TA; ja.lda[1] = 128; ja.ko[1] = 0;
    ja.p[2] = H1; ja.lda[2] = 256; ja.ko[2] = 0;
    ja.Wp = wb2b; ja.xs0 = ssq_pp; ja.xs1 = ssq_nn; ja.xs2 = hsq_b1;
    ja.hb = hb2b; ja.hbsq_p = hbsq + 2;
    ja.ob0 = TD; ja.ob1 = TA; ja.ldob = 128;
    ja.outf = nullptr; ja.ldof = 0; ja.ocol = 0; ja.hsq_out = hsq_b2;
    jh = ja;
    jh.p[0] = TE; jh.p[1] = TF; jh.ko[2] = 128;
    jh.Wp = wb2h; jh.xs0 = ssq_np; jh.xs1 = ssq_bn; jh.xs2 = hsq_n1;
    jh.hb = hb2h; jh.hbsq_p = hbsq + 3;
    jh.ob0 = TE; jh.ob1 = TF; jh.hsq_out = hsq_n2;
    gemm3_k<3, 4><<<dim3(gf, 2), 256, 0, stream>>>(ja, jh, N);
  }

  // ---- layer 3: hb2=[TD|TA] -> out[:,0:128]; hn2=[TE|TF] -> out[:,128:256] ----
  {
    GJob ja{}, jh{};
    ja.p[0] = TD; ja.lda[0] = 128; ja.ko[0] = 0;
    ja.p[1] = TA; ja.lda[1] = 128; ja.ko[1] = 0;
    ja.Wp = wb3b; ja.xs0 = hsq_b2; ja.xs1 = nullptr; ja.xs2 = nullptr;
    ja.hb = hb3b; ja.hbsq_p = hbsq + 4;
    ja.ob0 = nullptr; ja.ob1 = nullptr; ja.ldob = 0;
    ja.outf = outf; ja.ldof = 3 * D; ja.ocol = 0; ja.hsq_out = nullptr;
    jh = ja;
    jh.p[0] = TE; jh.p[1] = TF;
    jh.Wp = wb3h; jh.xs0 = hsq_n2;
    jh.hb = hb3h; jh.hbsq_p = hbsq + 5; jh.ocol = 128;
    gemm3_k<2, 2><<<dim3(gf, 2), 256, 0, stream>>>(ja, jh, N);
  }
}

// Round 10
// 864.800 us; speedup vs baseline: 1.1425x; 1.1425x over previous
//
#include <hip/hip_runtime.h>
#include <cstdint>
#include <cstddef>

#define DEV __device__ __forceinline__

typedef unsigned int uint32;
typedef unsigned short ushort16;
typedef __bf16 bfx8 __attribute__((ext_vector_type(8)));
typedef float f32x4 __attribute__((ext_vector_type(4)));

constexpr int D = 128;
constexpr int CAP = 64;               // max in-degree per list (Poisson(16): P(>64)~1e-20)
constexpr float MINN  = 1e-15f;
constexpr float MAXN  = 1.0f - 4e-3f; // (1 - BALL_EPS)/sqrt(c), c=1
constexpr float ACLIP = 1.0f - 1e-7f;

DEV float wave_sum(float v) {
#pragma unroll
  for (int off = 32; off > 0; off >>= 1) v += __shfl_xor(v, off, 64);
  return v;
}

DEV float artanh_clip(float x) {   // x >= 0 in all our uses
  x = fminf(x, ACLIP);
  return 0.5f * logf((1.0f + x) / (1.0f - x));
}

DEV uint32 f2b(float f) {          // fp32 -> bf16 RNE (low 16 bits)
  uint32 u = __float_as_uint(f);
  u += 0x7fffu + ((u >> 16) & 1u);
  return u >> 16;
}
DEV float b2f_lo(uint32 v) { return __uint_as_float(v << 16); }
DEV float b2f_hi(uint32 v) { return __uint_as_float(v & 0xffff0000u); }

// ---------------------------------------------------------------- bucket build
// Direct fixed-capacity bucket fill, XCD-partitioned (block%8 -> dst range),
// both edge lists in one dispatch (y = list). No hist/scan needed.
__global__ __launch_bounds__(256) void fillc_k(
    const int* __restrict__ sp, const int* __restrict__ dp,
    const int* __restrict__ sn, const int* __restrict__ dn, int E,
    int* __restrict__ cp, int* __restrict__ cn,
    int* __restrict__ lp, int* __restrict__ ln, int rngsz, int chunkE) {
  const int* __restrict__ src = blockIdx.y ? sn : sp;
  const int* __restrict__ dst = blockIdx.y ? dn : dp;
  int* __restrict__ cur = blockIdx.y ? cn : cp;
  int* __restrict__ lst = blockIdx.y ? ln : lp;
  const int r = blockIdx.x & 7;
  const int chunk = blockIdx.x >> 3;
  const unsigned lo = (unsigned)(r * rngsz);
  const int base = chunk * chunkE;
  const int end = min(base + chunkE, E);
  for (int i = base + (int)threadIdx.x; i < end; i += 256) {
    int d = dst[i];
    if ((unsigned)d - lo < (unsigned)rngsz) {
      int p = atomicAdd(&cur[d], 1);
      if (p < CAP) lst[(size_t)d * CAP + p] = src[i];
    }
  }
}

// ---------------------------------------------------------------- constants
// x -> xsq (rowsumsq) + bf16 copy + fp32 copy into d_out[:,256:384] + zero cur arrays
__global__ void rowsq_k(const float* __restrict__ x, float* __restrict__ xsq,
                        ushort16* __restrict__ xb, float* __restrict__ outx,
                        int* __restrict__ curz, int nz, int n) {
  int gid = blockIdx.x * 256 + (int)threadIdx.x;
  if (gid < nz) curz[gid] = 0;
  int lane = threadIdx.x & 63;
  int row = blockIdx.x * 4 + (threadIdx.x >> 6);
  if (row >= n) return;
  const float2 v = *(const float2*)(x + (size_t)row * D + lane * 2);
  uint32 pk = f2b(v.x) | (f2b(v.y) << 16);
  *(uint32*)(xb + (size_t)row * D + lane * 2) = pk;
  *(float2*)(outx + (size_t)row * 384 + 256 + lane * 2) = v;
  float s = wave_sum(v.x * v.x + v.y * v.y);
  if (lane == 0) xsq[row] = s;
}

// all six hyperbolic biases in one dispatch; block i handles bias i
struct BiasDesc { const float* b[6]; float* hb[6]; int dim[6]; };
__global__ void bias_all_k(BiasDesc bd, float* __restrict__ hbsq) {
  int i = blockIdx.x;
  int lane = threadIdx.x;
  const float* b = bd.b[i];
  float* hb = bd.hb[i];
  int ne = bd.dim[i] / 64;
  float v[4];
  float ssq = 0.0f;
  for (int e = 0; e < ne; ++e) { v[e] = b[e * 64 + lane]; ssq += v[e] * v[e]; }
  ssq = wave_sum(ssq);
  float nr = sqrtf(ssq);
  float nc = fmaxf(nr, MINN);
  float es = tanhf(nc) / nc;
  float on = es * nr;
  float f = (on > MAXN) ? (MAXN / fmaxf(on, MINN)) : 1.0f;
  float w = es * f;
  float osq = 0.0f;
  for (int e = 0; e < ne; ++e) { v[e] *= w; osq += v[e] * v[e]; hb[e * 64 + lane] = v[e]; }
  osq = wave_sum(osq);
  if (lane == 0) hbsq[i] = osq;
}

// W [DOUT,K] fp32 row-major -> bf16 MFMA-B fragment order:
// frag f = jt*(K/32)+kc; lane l holds B[col=jt*16+(l&15)][k=kc*32+(l>>4)*8 .. +7]
struct WsDesc { const float* src[6]; ushort16* dst[6]; int K[6]; int total[6]; };
__global__ void wshuf_all_k(WsDesc wd) {
  int y = blockIdx.y;
  int tid = blockIdx.x * 256 + threadIdx.x;
  if (tid >= wd.total[y]) return;
  int K = wd.K[y];
  int l = tid & 63;
  int fc = tid >> 6;
  int nkc = K / 32;
  int kc = fc % nkc;
  int jt = fc / nkc;
  int col = jt * 16 + (l & 15);
  int kb = kc * 32 + (l >> 4) * 8;
  const float* src = wd.src[y] + (size_t)col * K + kb;
  uint32 o[4];
#pragma unroll
  for (int m = 0; m < 4; ++m) o[m] = f2b(src[2 * m]) | (f2b(src[2 * m + 1]) << 16);
  *(uint4*)(wd.dst[y] + (size_t)tid * 8) = make_uint4(o[0], o[1], o[2], o[3]);
}

// ---------------------------------------------------------------- aggregation
// mean over fixed-capacity bucket; R7-proven config: one wave per row, uint2
// (8B/lane) gathers, 16-deep unroll, <=24 VGPR.
// NF=2: table rows are 512B [lo|hi]; lane l reads bytes l*8 -> lanes 0-31 produce
// the lo-half mean (OutLo/Slo), lanes 32-63 the hi-half (OutHi/Shi).
// NF=1: table rows 256B; lane group (l>>5) takes every other edge; fold at end.
struct AggJob {
  const char* T;                      // table base
  const int* cnt; const int* lst;
  ushort16* OutLo; ushort16* OutHi;   // 128-col bf16 rows
  float* Slo; float* Shi;
};

template <int NF>
__global__ __launch_bounds__(256) void agg2_k(AggJob ja, AggJob jbv, int n) {
  AggJob jb = blockIdx.y ? jbv : ja;
  const int l = threadIdx.x & 63;
  const int row = blockIdx.x * 4 + ((int)threadIdx.x >> 6);
  if (row >= n) return;
  const int cnt = jb.cnt[row];
  const int m = min(cnt, CAP);
  const int* __restrict__ lst = jb.lst + (size_t)row * CAP;
  const char* __restrict__ T = jb.T;
  float a0 = 0, a1 = 0, a2 = 0, a3 = 0;
  int j = 0;
  if (NF == 2) {
    const int off = l * 8;
    for (; j + 15 < m; j += 16) {
      uint2 v[16];
#pragma unroll
      for (int q = 0; q < 16; ++q)
        v[q] = *(const uint2*)(T + (size_t)lst[j + q] * 512 + off);
#pragma unroll
      for (int q = 0; q < 16; ++q) {
        a0 += b2f_lo(v[q].x); a1 += b2f_hi(v[q].x);
        a2 += b2f_lo(v[q].y); a3 += b2f_hi(v[q].y);
      }
    }
    for (; j + 3 < m; j += 4) {
      uint2 v[4];
#pragma unroll
      for (int q = 0; q < 4; ++q)
        v[q] = *(const uint2*)(T + (size_t)lst[j + q] * 512 + off);
#pragma unroll
      for (int q = 0; q < 4; ++q) {
        a0 += b2f_lo(v[q].x); a1 += b2f_hi(v[q].x);
        a2 += b2f_lo(v[q].y); a3 += b2f_hi(v[q].y);
      }
    }
    for (; j < m; ++j) {
      uint2 v = *(const uint2*)(T + (size_t)lst[j] * 512 + off);
      a0 += b2f_lo(v.x); a1 += b2f_hi(v.x);
      a2 += b2f_lo(v.y); a3 += b2f_hi(v.y);
    }
  } else {
    const int off = (l & 31) * 8;
    const int g = l >> 5;
    for (; j + 15 < m; j += 16) {
      uint2 v[8];
#pragma unroll
      for (int q = 0; q < 8; ++q)
        v[q] = *(const uint2*)(T + (size_t)lst[j + g + 2 * q] * 256 + off);
#pragma unroll
      for (int q = 0; q < 8; ++q) {
        a0 += b2f_lo(v[q].x); a1 += b2f_hi(v[q].x);
        a2 += b2f_lo(v[q].y); a3 += b2f_hi(v[q].y);
      }
    }
    for (; j + 1 < m; j += 2) {
      uint2 v = *(const uint2*)(T + (size_t)lst[j + g] * 256 + off);
      a0 += b2f_lo(v.x); a1 += b2f_hi(v.x);
      a2 += b2f_lo(v.y); a3 += b2f_hi(v.y);
    }
    if (j < m && g == 0) {
      uint2 v = *(const uint2*)(T + (size_t)lst[j] * 256 + off);
      a0 += b2f_lo(v.x); a1 += b2f_hi(v.x);
      a2 += b2f_lo(v.y); a3 += b2f_hi(v.y);
    }
    a0 += __shfl_xor(a0, 32, 64);
    a1 += __shfl_xor(a1, 32, 64);
    a2 += __shfl_xor(a2, 32, 64);
    a3 += __shfl_xor(a3, 32, 64);
  }
  float inv = 1.0f / fmaxf((float)cnt, 1.0f);
  a0 *= inv; a1 *= inv; a2 *= inv; a3 *= inv;
  float sq = a0 * a0 + a1 * a1 + a2 * a2 + a3 * a3;
#pragma unroll
  for (int o2 = 1; o2 < 32; o2 <<= 1) sq += __shfl_xor(sq, o2, 64);   // within 32-lane group
  uint2 o;
  o.x = f2b(a0) | (f2b(a1) << 16);
  o.y = f2b(a2) | (f2b(a3) << 16);
  if (NF == 2) {
    ushort16* Out = (l < 32) ? jb.OutLo : jb.OutHi;
    *(uint2*)((char*)Out + (size_t)row * 256 + (l & 31) * 8) = o;
    if (l == 0) jb.Slo[row] = sq;
    if (l == 32) jb.Shi[row] = sq;
  } else {
    if (l < 32) *(uint2*)((char*)jb.OutLo + (size_t)row * 256 + l * 8) = o;
    if (l == 0) jb.Slo[row] = sq;
  }
}

// ------------------------------------------------ bf16 MFMA GEMM + hyperbolic epilogue
// Two independent jobs per dispatch (blockIdx.y). Block: 64 rows x full dout.
// A = NC chunks of 128 k, register-prefetched; B direct from pre-shuffled W.
// bf16 output routed per 128-col group (ob0/ob1) so outputs may alias the
// row-aligned A-input tables (WAR-safe within a block; rows disjoint across blocks).
struct GJob {
  const ushort16* p[3];
  int lda[3], ko[3];
  const ushort16* Wp;
  const float *xs0, *xs1, *xs2;
  const float *hb, *hbsq_p;
  ushort16 *ob0, *ob1; int ldob;
  float* outf; int ldof, ocol;
  float* hsq_out;
};

template <int NC, int NCT>   // NCT: 2 -> dout=128, 4 -> dout=256
__global__ __launch_bounds__(256) void gemm3_k(GJob j0, GJob j1, int M) {
  GJob jb = blockIdx.y ? j1 : j0;
  __shared__ char As[16384];                 // [64 rows][128 k] bf16, XOR-swizzled
  __shared__ float hbs[NCT * 64];
  __shared__ float redA[4][64][2];
  __shared__ float redB[4][64];
  __shared__ float rs[64][4];
  const int t = threadIdx.x;
  const int l = t & 63;
  const int w = t >> 6;
  const int brow = blockIdx.x * 64;
  constexpr int KC32 = NC * 4;
  const int srow = t >> 4;
  const int sco = t & 15;

  for (int c = t; c < NCT * 64; c += 256) hbs[c] = jb.hb[c];

  auto gaddr = [&](int c, int h) -> const uint4* {
    int gr = min(brow + srow + h * 16, M - 1);   // clamp stays inside this block's rows
    return (const uint4*)(jb.p[c] + jb.ko[c] + (size_t)gr * jb.lda[c] + sco * 8);
  };

  f32x4 acc[4][NCT] = {};
  uint4 rga[4];
#pragma unroll
  for (int h = 0; h < 4; ++h) rga[h] = *gaddr(0, h);

#pragma unroll
  for (int c = 0; c < NC; ++c) {
#pragma unroll
    for (int h = 0; h < 4; ++h) {
      int row = srow + h * 16;
      *(uint4*)(As + row * 256 + ((sco * 16) ^ ((row & 7) << 4))) = rga[h];
    }
    __syncthreads();
    if (c + 1 < NC) {
#pragma unroll
      for (int h = 0; h < 4; ++h) rga[h] = *gaddr(c + 1, h);   // in flight during MFMA
    }
#pragma unroll
    for (int ks = 0; ks < 4; ++ks) {
      const int kb = ks * 64 + (l >> 4) * 16;
      bfx8 a[4], b[NCT];
#pragma unroll
      for (int j = 0; j < NCT; ++j)
        b[j] = *(const bfx8*)(jb.Wp + ((size_t)((w * NCT + j) * KC32 + c * 4 + ks)) * 512 + l * 8);
#pragma unroll
      for (int i = 0; i < 4; ++i) {
        int row = i * 16 + (l & 15);
        a[i] = *(const bfx8*)(As + row * 256 + (kb ^ ((row & 7) << 4)));
      }
#pragma unroll
      for (int i = 0; i < 4; ++i)
#pragma unroll
        for (int j = 0; j < NCT; ++j)
          acc[i][j] = __builtin_amdgcn_mfma_f32_16x16x32_bf16(a[i], b[j], acc[i][j], 0, 0, 0);
    }
    __syncthreads();
  }

  // ---- round A: per-row (||mx||^2, <mx,hb>) ----
#pragma unroll
  for (int i = 0; i < 4; ++i)
#pragma unroll
    for (int r = 0; r < 4; ++r) {
      float s = 0.0f, xy = 0.0f;
#pragma unroll
      for (int j = 0; j < NCT; ++j) {
        float m = acc[i][j][r];
        int col = w * (NCT * 16) + j * 16 + (l & 15);
        s += m * m;
        xy += m * hbs[col];
      }
#pragma unroll
      for (int off = 1; off < 16; off <<= 1) {
        s += __shfl_xor(s, off, 64);
        xy += __shfl_xor(xy, off, 64);
      }
      if ((l & 15) == 0) {
        int row = i * 16 + (l >> 4) * 4 + r;
        redA[w][row][0] = s;
        redA[w][row][1] = xy;
      }
    }
  __syncthreads();

  // ---- scalar phase 1 ----
  if (t < 64 && brow + t < M) {
    float ssq = redA[0][t][0] + redA[1][t][0] + redA[2][t][0] + redA[3][t][0];
    float xyr = redA[0][t][1] + redA[1][t][1] + redA[2][t][1] + redA[3][t][1];
    float mxn_raw = sqrtf(ssq);
    float xnsq = jb.xs0[brow + t];
    if (jb.xs1) xnsq += jb.xs1[brow + t];
    if (jb.xs2) xnsq += jb.xs2[brow + t];
    float xn = fmaxf(sqrtf(xnsq), MINN);
    float mxn = fmaxf(mxn_raw, MINN);
    float scal = tanhf(mxn / xn * artanh_clip(xn)) / mxn;
    float rn_raw = scal * mxn_raw;
    if (rn_raw > MAXN) { scal *= MAXN / fmaxf(rn_raw, MINN); rn_raw = MAXN; }
    float xyv = scal * xyr;
    float x2 = rn_raw * rn_raw;
    float y2 = *jb.hbsq_p;
    float den = fmaxf(1.0f + 2.0f * xyv + x2 * y2, MINN);
    float ax = (1.0f + 2.0f * xyv + y2) / den;
    float ay = (1.0f - x2) / den;
    float vsq = scal * scal * ssq;
    float psq = fmaxf(ax * ax * vsq + 2.0f * ax * ay * xyv + ay * ay * y2, 0.0f);
    float pn_raw = sqrtf(psq);
    float f2s = (pn_raw > MAXN) ? (MAXN / fmaxf(pn_raw, MINN)) : 1.0f;
    pn_raw = fminf(pn_raw, MAXN);
    float pn = fmaxf(pn_raw, MINN);
    float la = artanh_clip(pn) / pn * f2s;
    rs[t][0] = scal * ax;
    rs[t][1] = ay;
    rs[t][2] = la;
  }
  __syncthreads();

  // ---- round B: p = c1*mx + c2*hb; ppos = sum(relu(p)^2) ----
#pragma unroll
  for (int i = 0; i < 4; ++i)
#pragma unroll
    for (int r = 0; r < 4; ++r) {
      int row = i * 16 + (l >> 4) * 4 + r;
      float c1 = rs[row][0], c2 = rs[row][1];
      float pp = 0.0f;
#pragma unroll
      for (int j = 0; j < NCT; ++j) {
        int col = w * (NCT * 16) + j * 16 + (l & 15);
        float p = c1 * acc[i][j][r] + c2 * hbs[col];
        p = fmaxf(p, 0.0f);
        acc[i][j][r] = p;
        pp += p * p;
      }
#pragma unroll
      for (int off = 1; off < 16; off <<= 1) pp += __shfl_xor(pp, off, 64);
      if ((l & 15) == 0) redB[w][row] = pp;
    }
  __syncthreads();

  // ---- scalar phase 2 ----
  if (t < 64 && brow + t < M) {
    float ppos = redB[0][t] + redB[1][t] + redB[2][t] + redB[3][t];
    float la = rs[t][2];
    float tsq = la * la * ppos;
    float tn_raw = sqrtf(tsq);
    float tnc = fmaxf(tn_raw, MINN);
    float es = tanhf(tnc) / tnc;
    float on_raw = es * tn_raw;
    float f3 = (on_raw > MAXN) ? (MAXN / fmaxf(on_raw, MINN)) : 1.0f;
    float wsc = es * f3;
    float g = wsc * la;
    rs[t][3] = g;
    if (jb.hsq_out) jb.hsq_out[brow + t] = g * g * ppos;
  }
  __syncthreads();

  // ---- write out = g * relu(p) ----
#pragma unroll
  for (int i = 0; i < 4; ++i)
#pragma unroll
    for (int r = 0; r < 4; ++r) {
      int row = i * 16 + (l >> 4) * 4 + r;
      int gr = brow + row;
      if (gr < M) {
        float g = rs[row][3];
#pragma unroll
        for (int j = 0; j < NCT; ++j) {
          int col = w * (NCT * 16) + j * 16 + (l & 15);
          float o = g * acc[i][j][r];
          if (jb.ob0) {
            ushort16* ob = (col < 128) ? jb.ob0 : jb.ob1;
            ob[(size_t)gr * jb.ldob + (col & 127)] = (ushort16)f2b(o);
          } else {
            jb.outf[(size_t)gr * jb.ldof + jb.ocol + col] = o;
          }
        }
      }
    }
}

// ---------------------------------------------------------------- launcher
extern "C" void kernel_launch(void* const* d_in, const int* in_sizes, int n_in,
                              void* d_out, int out_size, void* d_ws, size_t ws_size,
                              hipStream_t stream) {
  const float* x = (const float*)d_in[0];
  const int* src_pos = (const int*)d_in[1];
  const int* dst_pos = (const int*)d_in[2];
  const int* src_neg = (const int*)d_in[3];
  const int* dst_neg = (const int*)d_in[4];
  const float* W1b = (const float*)d_in[5];
  const float* b1b = (const float*)d_in[6];
  const float* W1h = (const float*)d_in[7];
  const float* b1h = (const float*)d_in[8];
  const float* W2b = (const float*)d_in[9];
  const float* b2b = (const float*)d_in[10];
  const float* W2h = (const float*)d_in[11];
  const float* b2h = (const float*)d_in[12];
  const float* W3b = (const float*)d_in[13];
  const float* b3b = (const float*)d_in[14];
  const float* W3h = (const float*)d_in[15];
  const float* b3h = (const float*)d_in[16];

  const int N = in_sizes[0] / D;   // 100000
  const int E = in_sizes[1];       // 1600000

  // ---- workspace: ints | fp32 | bf16 ----
  int* iw = (int*)d_ws;
  size_t io = 0;
  int* cur_p = iw + io;  io += N;
  int* cur_n = iw + io;  io += N;
  int* lst_p = iw + io;  io += (size_t)N * CAP;
  int* lst_n = iw + io;  io += (size_t)N * CAP;
  io = (io + 63) & ~(size_t)63;

  float* fw = (float*)(iw + io);
  size_t fo = 0;
  float* xsq = fw + fo;    fo += N;
  float* hsq_b1 = fw + fo; fo += N;
  float* hsq_n1 = fw + fo; fo += N;
  float* hsq_b2 = fw + fo; fo += N;
  float* hsq_n2 = fw + fo; fo += N;
  float* ssq_p1 = fw + fo; fo += N;
  float* ssq_n1 = fw + fo; fo += N;
  float* ssq_pp = fw + fo; fo += N;   // ||A_P(hb1)||^2
  float* ssq_np = fw + fo; fo += N;   // ||A_P(hn1)||^2
  float* ssq_nn = fw + fo; fo += N;   // ||A_N(hn1)||^2
  float* ssq_bn = fw + fo; fo += N;   // ||A_N(hb1)||^2
  float* hbase = fw + fo;  fo += 1056;
  fo = (fo + 31) & ~(size_t)31;

  ushort16* SB = (ushort16*)(fw + fo);
  const size_t NSB = (size_t)N * D;
  ushort16* TA = SB;             // xb          -> A_N(hn1) -> HB2 hi
  ushort16* H1 = SB + NSB;       // [N,256] hb1|hn1 interleaved (2 slots)
  ushort16* TD = SB + 3 * NSB;   // A_P(x)  -> A_P(hb1) -> HB2 lo
  ushort16* TE = SB + 4 * NSB;   // A_N(x)  -> A_P(hn1) -> HN2 lo
  ushort16* TF = SB + 5 * NSB;   //            A_N(hb1) -> HN2 hi
  ushort16* wb1b = SB + 6 * NSB;
  ushort16* wb1h = wb1b + 32768;
  ushort16* wb2b = wb1h + 32768;
  ushort16* wb2h = wb2b + 98304;
  ushort16* wb3b = wb2h + 98304;
  ushort16* wb3h = wb3b + 32768;

  float* outf = (float*)d_out;

  float* hb1b = hbase + 0;
  float* hb1h = hbase + 128;
  float* hb2b = hbase + 256;
  float* hb2h = hbase + 512;
  float* hb3b = hbase + 768;
  float* hb3h = hbase + 896;
  float* hbsq = hbase + 1024;

  const int grow = (N + 3) / 4;
  const int gf = (N + 63) / 64;
  const int rngsz = (N + 7) / 8;
  const int chunkE = (E + 255) / 256;
  const int gpart = 256 * 8;

  // ---- constants + cur zeroing (rowsq precedes fillc) ----
  rowsq_k<<<grow, 256, 0, stream>>>(x, xsq, TA, outf, cur_p, 2 * N, N);
  fillc_k<<<dim3(gpart, 2), 256, 0, stream>>>(src_pos, dst_pos, src_neg, dst_neg, E,
                                              cur_p, cur_n, lst_p, lst_n, rngsz, chunkE);
  {
    BiasDesc bd;
    bd.b[0] = b1b; bd.hb[0] = hb1b; bd.dim[0] = 128;
    bd.b[1] = b1h; bd.hb[1] = hb1h; bd.dim[1] = 128;
    bd.b[2] = b2b; bd.hb[2] = hb2b; bd.dim[2] = 256;
    bd.b[3] = b2h; bd.hb[3] = hb2h; bd.dim[3] = 256;
    bd.b[4] = b3b; bd.hb[4] = hb3b; bd.dim[4] = 128;
    bd.b[5] = b3h; bd.hb[5] = hb3h; bd.dim[5] = 128;
    bias_all_k<<<6, 64, 0, stream>>>(bd, hbsq);
  }
  {
    WsDesc wd;
    wd.src[0] = W1b; wd.dst[0] = wb1b; wd.K[0] = 256; wd.total[0] = 8 * 8 * 64;
    wd.src[1] = W1h; wd.dst[1] = wb1h; wd.K[1] = 256; wd.total[1] = 8 * 8 * 64;
    wd.src[2] = W2b; wd.dst[2] = wb2b; wd.K[2] = 384; wd.total[2] = 16 * 12 * 64;
    wd.src[3] = W2h; wd.dst[3] = wb2h; wd.K[3] = 384; wd.total[3] = 16 * 12 * 64;
    wd.src[4] = W3b; wd.dst[4] = wb3b; wd.K[4] = 256; wd.total[4] = 8 * 8 * 64;
    wd.src[5] = W3h; wd.dst[5] = wb3h; wd.K[5] = 256; wd.total[5] = 8 * 8 * 64;
    wshuf_all_k<<<dim3(48, 6), 256, 0, stream>>>(wd);
  }

  // ---- layer 1 aggs: A_P(x)->TD, A_N(x)->TE ----
  {
    AggJob jp{(const char*)TA, cur_p, lst_p, TD, nullptr, ssq_p1, nullptr};
    AggJob jn{(const char*)TA, cur_n, lst_n, TE, nullptr, ssq_n1, nullptr};
    agg2_k<1><<<dim3(grow, 2), 256, 0, stream>>>(jp, jn, N);
  }
  // ---- layer 1 gemms: write hb1|hn1 interleaved into H1 ----
  {
    GJob ja{}, jh{};
    ja.p[0] = TD; ja.lda[0] = 128; ja.ko[0] = 0;
    ja.p[1] = TA; ja.lda[1] = 128; ja.ko[1] = 0;
    ja.Wp = wb1b; ja.xs0 = ssq_p1; ja.xs1 = xsq; ja.xs2 = nullptr;
    ja.hb = hb1b; ja.hbsq_p = hbsq + 0;
    ja.ob0 = H1; ja.ob1 = nullptr; ja.ldob = 256;
    ja.outf = nullptr; ja.ldof = 0; ja.ocol = 0; ja.hsq_out = hsq_b1;
    jh = ja;
    jh.p[0] = TE; jh.Wp = wb1h; jh.xs0 = ssq_n1;
    jh.hb = hb1h; jh.hbsq_p = hbsq + 1; jh.ob0 = H1 + 128; jh.hsq_out = hsq_n1;
    gemm3_k<2, 2><<<dim3(gf, 2), 256, 0, stream>>>(ja, jh, N);
  }

  // ---- layer 2 aggs over interleaved H1 (lo half = hb1, hi half = hn1) ----
  {
    // P job: OutLo = A_P(hb1)=TD, OutHi = A_P(hn1)=TE
    AggJob jp{(const char*)H1, cur_p, lst_p, TD, TE, ssq_pp, ssq_np};
    // N job: OutLo = A_N(hb1)=TF, OutHi = A_N(hn1)=TA
    AggJob jn{(const char*)H1, cur_n, lst_n, TF, TA, ssq_bn, ssq_nn};
    agg2_k<2><<<dim3(grow, 2), 256, 0, stream>>>(jp, jn, N);
  }
  // ---- layer 2 gemms: HB2 -> [TD|TA], HN2 -> [TE|TF] (alias inputs, row-aligned) ----
  {
    GJob ja{}, jh{};
    ja.p[0] = TD; ja.lda[0] = 128; ja.ko[0] = 0;
    ja.p[1] = TA; ja.lda[1] = 128; ja.ko[1] = 0;
    ja.p[2] = H1; ja.lda[2] = 256; ja.ko[2] = 0;
    ja.Wp = wb2b; ja.xs0 = ssq_pp; ja.xs1 = ssq_nn; ja.xs2 = hsq_b1;
    ja.hb = hb2b; ja.hbsq_p = hbsq + 2;
    ja.ob0 = TD; ja.ob1 = TA; ja.ldob = 128;
    ja.outf = nullptr; ja.ldof = 0; ja.ocol = 0; ja.hsq_out = hsq_b2;
    jh = ja;
    jh.p[0] = TE; jh.p[1] = TF; jh.ko[2] = 128;
    jh.Wp = wb2h; jh.xs0 = ssq_np; jh.xs1 = ssq_bn; jh.xs2 = hsq_n1;
    jh.hb = hb2h; jh.hbsq_p = hbsq + 3;
    jh.ob0 = TE; jh.ob1 = TF; jh.hsq_out = hsq_n2;
    gemm3_k<3, 4><<<dim3(gf, 2), 256, 0, stream>>>(ja, jh, N);
  }

  // ---- layer 3: hb2=[TD|TA] -> out[:,0:128]; hn2=[TE|TF] -> out[:,128:256] ----
  {
    GJob ja{}, jh{};
    ja.p[0] = TD; ja.lda[0] = 128; ja.ko[0] = 0;
    ja.p[1] = TA; ja.lda[1] = 128; ja.ko[1] = 0;
    ja.Wp = wb3b; ja.xs0 = hsq_b2; ja.xs1 = nullptr; ja.xs2 = nullptr;
    ja.hb = hb3b; ja.hbsq_p = hbsq + 4;
    ja.ob0 = nullptr; ja.ob1 = nullptr; ja.ldob = 0;
    ja.outf = outf; ja.ldof = 3 * D; ja.ocol = 0; ja.hsq_out = nullptr;
    jh = ja;
    jh.p[0] = TE; jh.p[1] = TF;
    jh.Wp = wb3h; jh.xs0 = hsq_n2;
    jh.hb = hb3h; jh.hbsq_p = hbsq + 5; jh.ocol = 128;
    gemm3_k<2, 2><<<dim3(gf, 2), 256, 0, stream>>>(ja, jh, N);
  }
}

// Round 11
// 854.722 us; speedup vs baseline: 1.1560x; 1.0118x over previous
//
#include <hip/hip_runtime.h>
#include <cstdint>
#include <cstddef>

#define DEV __device__ __forceinline__

typedef unsigned int uint32;
typedef unsigned short ushort16;
typedef __bf16 bfx8 __attribute__((ext_vector_type(8)));
typedef float f32x4 __attribute__((ext_vector_type(4)));

constexpr int D = 128;
constexpr int CAP = 64;               // max in-degree per list (Poisson(16): P(>64)~1e-20)
constexpr float MINN  = 1e-15f;
constexpr float MAXN  = 1.0f - 4e-3f; // (1 - BALL_EPS)/sqrt(c), c=1
constexpr float ACLIP = 1.0f - 1e-7f;

DEV float wave_sum(float v) {
#pragma unroll
  for (int off = 32; off > 0; off >>= 1) v += __shfl_xor(v, off, 64);
  return v;
}

DEV float artanh_clip(float x) {   // x >= 0 in all our uses
  x = fminf(x, ACLIP);
  return 0.5f * logf((1.0f + x) / (1.0f - x));
}

DEV uint32 f2b(float f) {          // fp32 -> bf16 RNE (low 16 bits)
  uint32 u = __float_as_uint(f);
  u += 0x7fffu + ((u >> 16) & 1u);
  return u >> 16;
}
DEV float b2f_lo(uint32 v) { return __uint_as_float(v << 16); }
DEV float b2f_hi(uint32 v) { return __uint_as_float(v & 0xffff0000u); }

// ---------------------------------------------------------------- bucket build
// Direct fixed-capacity bucket fill, XCD-partitioned (block%8 -> dst range),
// both edge lists in one dispatch (y = list). No hist/scan needed.
__global__ __launch_bounds__(256) void fillc_k(
    const int* __restrict__ sp, const int* __restrict__ dp,
    const int* __restrict__ sn, const int* __restrict__ dn, int E,
    int* __restrict__ cp, int* __restrict__ cn,
    int* __restrict__ lp, int* __restrict__ ln, int rngsz, int chunkE) {
  const int* __restrict__ src = blockIdx.y ? sn : sp;
  const int* __restrict__ dst = blockIdx.y ? dn : dp;
  int* __restrict__ cur = blockIdx.y ? cn : cp;
  int* __restrict__ lst = blockIdx.y ? ln : lp;
  const int r = blockIdx.x & 7;
  const int chunk = blockIdx.x >> 3;
  const unsigned lo = (unsigned)(r * rngsz);
  const int base = chunk * chunkE;
  const int end = min(base + chunkE, E);
  for (int i = base + (int)threadIdx.x; i < end; i += 256) {
    int d = dst[i];
    if ((unsigned)d - lo < (unsigned)rngsz) {
      int p = atomicAdd(&cur[d], 1);
      if (p < CAP) lst[(size_t)d * CAP + p] = src[i];
    }
  }
}

// ---------------------------------------------------------------- constants
// x -> xsq (rowsumsq) + bf16 copy + fp32 copy into d_out[:,256:384] + zero cur arrays
__global__ void rowsq_k(const float* __restrict__ x, float* __restrict__ xsq,
                        ushort16* __restrict__ xb, float* __restrict__ outx,
                        int* __restrict__ curz, int nz, int n) {
  int gid = blockIdx.x * 256 + (int)threadIdx.x;
  if (gid < nz) curz[gid] = 0;
  int lane = threadIdx.x & 63;
  int row = blockIdx.x * 4 + (threadIdx.x >> 6);
  if (row >= n) return;
  const float2 v = *(const float2*)(x + (size_t)row * D + lane * 2);
  uint32 pk = f2b(v.x) | (f2b(v.y) << 16);
  *(uint32*)(xb + (size_t)row * D + lane * 2) = pk;
  *(float2*)(outx + (size_t)row * 384 + 256 + lane * 2) = v;
  float s = wave_sum(v.x * v.x + v.y * v.y);
  if (lane == 0) xsq[row] = s;
}

// all six hyperbolic biases in one dispatch; block i handles bias i
struct BiasDesc { const float* b[6]; float* hb[6]; int dim[6]; };
__global__ void bias_all_k(BiasDesc bd, float* __restrict__ hbsq) {
  int i = blockIdx.x;
  int lane = threadIdx.x;
  const float* b = bd.b[i];
  float* hb = bd.hb[i];
  int ne = bd.dim[i] / 64;
  float v[4];
  float ssq = 0.0f;
  for (int e = 0; e < ne; ++e) { v[e] = b[e * 64 + lane]; ssq += v[e] * v[e]; }
  ssq = wave_sum(ssq);
  float nr = sqrtf(ssq);
  float nc = fmaxf(nr, MINN);
  float es = tanhf(nc) / nc;
  float on = es * nr;
  float f = (on > MAXN) ? (MAXN / fmaxf(on, MINN)) : 1.0f;
  float w = es * f;
  float osq = 0.0f;
  for (int e = 0; e < ne; ++e) { v[e] *= w; osq += v[e] * v[e]; hb[e * 64 + lane] = v[e]; }
  osq = wave_sum(osq);
  if (lane == 0) hbsq[i] = osq;
}

// W [DOUT,K] fp32 row-major -> bf16 MFMA-B fragment order:
// frag f = jt*(K/32)+kc; lane l holds B[col=jt*16+(l&15)][k=kc*32+(l>>4)*8 .. +7]
struct WsDesc { const float* src[6]; ushort16* dst[6]; int K[6]; int total[6]; };
__global__ void wshuf_all_k(WsDesc wd) {
  int y = blockIdx.y;
  int tid = blockIdx.x * 256 + threadIdx.x;
  if (tid >= wd.total[y]) return;
  int K = wd.K[y];
  int l = tid & 63;
  int fc = tid >> 6;
  int nkc = K / 32;
  int kc = fc % nkc;
  int jt = fc / nkc;
  int col = jt * 16 + (l & 15);
  int kb = kc * 32 + (l >> 4) * 8;
  const float* src = wd.src[y] + (size_t)col * K + kb;
  uint32 o[4];
#pragma unroll
  for (int m = 0; m < 4; ++m) o[m] = f2b(src[2 * m]) | (f2b(src[2 * m + 1]) << 16);
  *(uint4*)(wd.dst[y] + (size_t)tid * 8) = make_uint4(o[0], o[1], o[2], o[3]);
}

// ---------------------------------------------------------------- aggregation
// mean over fixed-capacity bucket (bf16 in, bf16 out + fp32 rowsumsq of mean);
// wave per row; two jobs (P/N list) per dispatch via blockIdx.y.
// R7-proven config: uint32 loads at ofs0/ofs1, 4-deep unroll, ~24 VGPR, 79% occ.
// NF=2 reads two 128-col halves of one interleaved [lda] row (ofs0, ofs1).
struct AggJob {
  const ushort16* T; int lda; int ofs0; int ofs1;
  const int* cnt; const int* lst;
  ushort16* O0; ushort16* O1;
  float* S0; float* S1;
};

template <int NF>
__global__ __launch_bounds__(256) void agg2_k(AggJob ja, AggJob jbv, int n) {
  AggJob jb = blockIdx.y ? jbv : ja;
  int lane = threadIdx.x & 63;
  int row = blockIdx.x * 4 + ((int)threadIdx.x >> 6);
  if (row >= n) return;
  int cnt = jb.cnt[row];
  int m = min(cnt, CAP);
  const int* __restrict__ lst = jb.lst + (size_t)row * CAP;
  const ushort16* __restrict__ T = jb.T;
  const int lda = jb.lda;
  const int o0 = jb.ofs0 + lane * 2;
  const int o1 = jb.ofs1 + lane * 2;
  float a0 = 0, b0 = 0, a1 = 0, b1 = 0;
  int j = 0;
  for (; j + 3 < m; j += 4) {
    size_t r0 = (size_t)lst[j] * lda, r1 = (size_t)lst[j + 1] * lda;
    size_t r2 = (size_t)lst[j + 2] * lda, r3 = (size_t)lst[j + 3] * lda;
    uint32 u0 = *(const uint32*)(T + r0 + o0);
    uint32 u1 = *(const uint32*)(T + r1 + o0);
    uint32 u2 = *(const uint32*)(T + r2 + o0);
    uint32 u3 = *(const uint32*)(T + r3 + o0);
    if (NF == 2) {
      uint32 w0 = *(const uint32*)(T + r0 + o1);
      uint32 w1 = *(const uint32*)(T + r1 + o1);
      uint32 w2 = *(const uint32*)(T + r2 + o1);
      uint32 w3 = *(const uint32*)(T + r3 + o1);
      a1 += b2f_lo(w0) + b2f_lo(w1) + b2f_lo(w2) + b2f_lo(w3);
      b1 += b2f_hi(w0) + b2f_hi(w1) + b2f_hi(w2) + b2f_hi(w3);
    }
    a0 += b2f_lo(u0) + b2f_lo(u1) + b2f_lo(u2) + b2f_lo(u3);
    b0 += b2f_hi(u0) + b2f_hi(u1) + b2f_hi(u2) + b2f_hi(u3);
  }
  for (; j < m; ++j) {
    size_t r0 = (size_t)lst[j] * lda;
    uint32 u0 = *(const uint32*)(T + r0 + o0);
    a0 += b2f_lo(u0); b0 += b2f_hi(u0);
    if (NF == 2) {
      uint32 w0 = *(const uint32*)(T + r0 + o1);
      a1 += b2f_lo(w0); b1 += b2f_hi(w0);
    }
  }
  float inv = 1.0f / fmaxf((float)cnt, 1.0f);
  a0 *= inv; b0 *= inv;
  float s = wave_sum(a0 * a0 + b0 * b0);
  *(uint32*)(jb.O0 + (size_t)row * D + lane * 2) = f2b(a0) | (f2b(b0) << 16);
  if (lane == 0) jb.S0[row] = s;
  if (NF == 2) {
    a1 *= inv; b1 *= inv;
    float s1 = wave_sum(a1 * a1 + b1 * b1);
    *(uint32*)(jb.O1 + (size_t)row * D + lane * 2) = f2b(a1) | (f2b(b1) << 16);
    if (lane == 0) jb.S1[row] = s1;
  }
}

// ------------------------------------------------ bf16 MFMA GEMM + hyperbolic epilogue
// Two independent jobs per dispatch (blockIdx.y). Block: 64 rows x full dout.
// A = NC chunks of 128 k, register-prefetched; B direct from pre-shuffled W.
// bf16 output routed per 128-col group (ob0/ob1) so outputs may alias the
// row-aligned A-input tables (WAR-safe within a block; rows disjoint across blocks).
struct GJob {
  const ushort16* p[3];
  int lda[3], ko[3];
  const ushort16* Wp;
  const float *xs0, *xs1, *xs2;
  const float *hb, *hbsq_p;
  ushort16 *ob0, *ob1; int ldob;
  float* outf; int ldof, ocol;
  float* hsq_out;
};

template <int NC, int NCT>   // NCT: 2 -> dout=128, 4 -> dout=256
__global__ __launch_bounds__(256) void gemm3_k(GJob j0, GJob j1, int M) {
  GJob jb = blockIdx.y ? j1 : j0;
  __shared__ char As[16384];                 // [64 rows][128 k] bf16, XOR-swizzled
  __shared__ float hbs[NCT * 64];
  __shared__ float redA[4][64][2];
  __shared__ float redB[4][64];
  __shared__ float rs[64][4];
  const int t = threadIdx.x;
  const int l = t & 63;
  const int w = t >> 6;
  const int brow = blockIdx.x * 64;
  constexpr int KC32 = NC * 4;
  const int srow = t >> 4;
  const int sco = t & 15;

  for (int c = t; c < NCT * 64; c += 256) hbs[c] = jb.hb[c];

  auto gaddr = [&](int c, int h) -> const uint4* {
    int gr = min(brow + srow + h * 16, M - 1);   // clamp stays inside this block's rows
    return (const uint4*)(jb.p[c] + jb.ko[c] + (size_t)gr * jb.lda[c] + sco * 8);
  };

  f32x4 acc[4][NCT] = {};
  uint4 rga[4];
#pragma unroll
  for (int h = 0; h < 4; ++h) rga[h] = *gaddr(0, h);

#pragma unroll
  for (int c = 0; c < NC; ++c) {
#pragma unroll
    for (int h = 0; h < 4; ++h) {
      int row = srow + h * 16;
      *(uint4*)(As + row * 256 + ((sco * 16) ^ ((row & 7) << 4))) = rga[h];
    }
    __syncthreads();
    if (c + 1 < NC) {
#pragma unroll
      for (int h = 0; h < 4; ++h) rga[h] = *gaddr(c + 1, h);   // in flight during MFMA
    }
#pragma unroll
    for (int ks = 0; ks < 4; ++ks) {
      const int kb = ks * 64 + (l >> 4) * 16;
      bfx8 a[4], b[NCT];
#pragma unroll
      for (int j = 0; j < NCT; ++j)
        b[j] = *(const bfx8*)(jb.Wp + ((size_t)((w * NCT + j) * KC32 + c * 4 + ks)) * 512 + l * 8);
#pragma unroll
      for (int i = 0; i < 4; ++i) {
        int row = i * 16 + (l & 15);
        a[i] = *(const bfx8*)(As + row * 256 + (kb ^ ((row & 7) << 4)));
      }
#pragma unroll
      for (int i = 0; i < 4; ++i)
#pragma unroll
        for (int j = 0; j < NCT; ++j)
          acc[i][j] = __builtin_amdgcn_mfma_f32_16x16x32_bf16(a[i], b[j], acc[i][j], 0, 0, 0);
    }
    __syncthreads();
  }

  // ---- round A: per-row (||mx||^2, <mx,hb>) ----
#pragma unroll
  for (int i = 0; i < 4; ++i)
#pragma unroll
    for (int r = 0; r < 4; ++r) {
      float s = 0.0f, xy = 0.0f;
#pragma unroll
      for (int j = 0; j < NCT; ++j) {
        float m = acc[i][j][r];
        int col = w * (NCT * 16) + j * 16 + (l & 15);
        s += m * m;
        xy += m * hbs[col];
      }
#pragma unroll
      for (int off = 1; off < 16; off <<= 1) {
        s += __shfl_xor(s, off, 64);
        xy += __shfl_xor(xy, off, 64);
      }
      if ((l & 15) == 0) {
        int row = i * 16 + (l >> 4) * 4 + r;
        redA[w][row][0] = s;
        redA[w][row][1] = xy;
      }
    }
  __syncthreads();

  // ---- scalar phase 1 ----
  if (t < 64 && brow + t < M) {
    float ssq = redA[0][t][0] + redA[1][t][0] + redA[2][t][0] + redA[3][t][0];
    float xyr = redA[0][t][1] + redA[1][t][1] + redA[2][t][1] + redA[3][t][1];
    float mxn_raw = sqrtf(ssq);
    float xnsq = jb.xs0[brow + t];
    if (jb.xs1) xnsq += jb.xs1[brow + t];
    if (jb.xs2) xnsq += jb.xs2[brow + t];
    float xn = fmaxf(sqrtf(xnsq), MINN);
    float mxn = fmaxf(mxn_raw, MINN);
    float scal = tanhf(mxn / xn * artanh_clip(xn)) / mxn;
    float rn_raw = scal * mxn_raw;
    if (rn_raw > MAXN) { scal *= MAXN / fmaxf(rn_raw, MINN); rn_raw = MAXN; }
    float xyv = scal * xyr;
    float x2 = rn_raw * rn_raw;
    float y2 = *jb.hbsq_p;
    float den = fmaxf(1.0f + 2.0f * xyv + x2 * y2, MINN);
    float ax = (1.0f + 2.0f * xyv + y2) / den;
    float ay = (1.0f - x2) / den;
    float vsq = scal * scal * ssq;
    float psq = fmaxf(ax * ax * vsq + 2.0f * ax * ay * xyv + ay * ay * y2, 0.0f);
    float pn_raw = sqrtf(psq);
    float f2s = (pn_raw > MAXN) ? (MAXN / fmaxf(pn_raw, MINN)) : 1.0f;
    pn_raw = fminf(pn_raw, MAXN);
    float pn = fmaxf(pn_raw, MINN);
    float la = artanh_clip(pn) / pn * f2s;
    rs[t][0] = scal * ax;
    rs[t][1] = ay;
    rs[t][2] = la;
  }
  __syncthreads();

  // ---- round B: p = c1*mx + c2*hb; ppos = sum(relu(p)^2) ----
#pragma unroll
  for (int i = 0; i < 4; ++i)
#pragma unroll
    for (int r = 0; r < 4; ++r) {
      int row = i * 16 + (l >> 4) * 4 + r;
      float c1 = rs[row][0], c2 = rs[row][1];
      float pp = 0.0f;
#pragma unroll
      for (int j = 0; j < NCT; ++j) {
        int col = w * (NCT * 16) + j * 16 + (l & 15);
        float p = c1 * acc[i][j][r] + c2 * hbs[col];
        p = fmaxf(p, 0.0f);
        acc[i][j][r] = p;
        pp += p * p;
      }
#pragma unroll
      for (int off = 1; off < 16; off <<= 1) pp += __shfl_xor(pp, off, 64);
      if ((l & 15) == 0) redB[w][row] = pp;
    }
  __syncthreads();

  // ---- scalar phase 2 ----
  if (t < 64 && brow + t < M) {
    float ppos = redB[0][t] + redB[1][t] + redB[2][t] + redB[3][t];
    float la = rs[t][2];
    float tsq = la * la * ppos;
    float tn_raw = sqrtf(tsq);
    float tnc = fmaxf(tn_raw, MINN);
    float es = tanhf(tnc) / tnc;
    float on_raw = es * tn_raw;
    float f3 = (on_raw > MAXN) ? (MAXN / fmaxf(on_raw, MINN)) : 1.0f;
    float wsc = es * f3;
    float g = wsc * la;
    rs[t][3] = g;
    if (jb.hsq_out) jb.hsq_out[brow + t] = g * g * ppos;
  }
  __syncthreads();

  // ---- write out = g * relu(p) ----
#pragma unroll
  for (int i = 0; i < 4; ++i)
#pragma unroll
    for (int r = 0; r < 4; ++r) {
      int row = i * 16 + (l >> 4) * 4 + r;
      int gr = brow + row;
      if (gr < M) {
        float g = rs[row][3];
#pragma unroll
        for (int j = 0; j < NCT; ++j) {
          int col = w * (NCT * 16) + j * 16 + (l & 15);
          float o = g * acc[i][j][r];
          if (jb.ob0) {
            ushort16* ob = (col < 128) ? jb.ob0 : jb.ob1;
            ob[(size_t)gr * jb.ldob + (col & 127)] = (ushort16)f2b(o);
          } else {
            jb.outf[(size_t)gr * jb.ldof + jb.ocol + col] = o;
          }
        }
      }
    }
}

// ---------------------------------------------------------------- launcher
extern "C" void kernel_launch(void* const* d_in, const int* in_sizes, int n_in,
                              void* d_out, int out_size, void* d_ws, size_t ws_size,
                              hipStream_t stream) {
  const float* x = (const float*)d_in[0];
  const int* src_pos = (const int*)d_in[1];
  const int* dst_pos = (const int*)d_in[2];
  const int* src_neg = (const int*)d_in[3];
  const int* dst_neg = (const int*)d_in[4];
  const float* W1b = (const float*)d_in[5];
  const float* b1b = (const float*)d_in[6];
  const float* W1h = (const float*)d_in[7];
  const float* b1h = (const float*)d_in[8];
  const float* W2b = (const float*)d_in[9];
  const float* b2b = (const float*)d_in[10];
  const float* W2h = (const float*)d_in[11];
  const float* b2h = (const float*)d_in[12];
  const float* W3b = (const float*)d_in[13];
  const float* b3b = (const float*)d_in[14];
  const float* W3h = (const float*)d_in[15];
  const float* b3h = (const float*)d_in[16];

  const int N = in_sizes[0] / D;   // 100000
  const int E = in_sizes[1];       // 1600000

  // ---- workspace: ints | fp32 | bf16 ----
  int* iw = (int*)d_ws;
  size_t io = 0;
  int* cur_p = iw + io;  io += N;
  int* cur_n = iw + io;  io += N;
  int* lst_p = iw + io;  io += (size_t)N * CAP;
  int* lst_n = iw + io;  io += (size_t)N * CAP;
  io = (io + 63) & ~(size_t)63;

  float* fw = (float*)(iw + io);
  size_t fo = 0;
  float* xsq = fw + fo;    fo += N;
  float* hsq_b1 = fw + fo; fo += N;
  float* hsq_n1 = fw + fo; fo += N;
  float* hsq_b2 = fw + fo; fo += N;
  float* hsq_n2 = fw + fo; fo += N;
  float* ssq_p1 = fw + fo; fo += N;
  float* ssq_n1 = fw + fo; fo += N;
  float* ssq_pp = fw + fo; fo += N;   // ||A_P(hb1)||^2
  float* ssq_np = fw + fo; fo += N;   // ||A_P(hn1)||^2
  float* ssq_nn = fw + fo; fo += N;   // ||A_N(hn1)||^2
  float* ssq_bn = fw + fo; fo += N;   // ||A_N(hb1)||^2
  float* hbase = fw + fo;  fo += 1056;
  fo = (fo + 31) & ~(size_t)31;

  ushort16* SB = (ushort16*)(fw + fo);
  const size_t NSB = (size_t)N * D;
  ushort16* TA = SB;             // xb          -> A_N(hn1) -> HB2 hi
  ushort16* H1 = SB + NSB;       // [N,256] hb1|hn1 interleaved (2 slots)
  ushort16* TD = SB + 3 * NSB;   // A_P(x)  -> A_P(hb1) -> HB2 lo
  ushort16* TE = SB + 4 * NSB;   // A_N(x)  -> A_P(hn1) -> HN2 lo
  ushort16* TF = SB + 5 * NSB;   //            A_N(hb1) -> HN2 hi
  ushort16* wb1b = SB + 6 * NSB;
  ushort16* wb1h = wb1b + 32768;
  ushort16* wb2b = wb1h + 32768;
  ushort16* wb2h = wb2b + 98304;
  ushort16* wb3b = wb2h + 98304;
  ushort16* wb3h = wb3b + 32768;

  float* outf = (float*)d_out;

  float* hb1b = hbase + 0;
  float* hb1h = hbase + 128;
  float* hb2b = hbase + 256;
  float* hb2h = hbase + 512;
  float* hb3b = hbase + 768;
  float* hb3h = hbase + 896;
  float* hbsq = hbase + 1024;

  const int grow = (N + 3) / 4;
  const int gf = (N + 63) / 64;
  const int rngsz = (N + 7) / 8;
  const int chunkE = (E + 255) / 256;
  const int gpart = 256 * 8;

  // ---- constants + cur zeroing (rowsq precedes fillc) ----
  rowsq_k<<<grow, 256, 0, stream>>>(x, xsq, TA, outf, cur_p, 2 * N, N);
  fillc_k<<<dim3(gpart, 2), 256, 0, stream>>>(src_pos, dst_pos, src_neg, dst_neg, E,
                                              cur_p, cur_n, lst_p, lst_n, rngsz, chunkE);
  {
    BiasDesc bd;
    bd.b[0] = b1b; bd.hb[0] = hb1b; bd.dim[0] = 128;
    bd.b[1] = b1h; bd.hb[1] = hb1h; bd.dim[1] = 128;
    bd.b[2] = b2b; bd.hb[2] = hb2b; bd.dim[2] = 256;
    bd.b[3] = b2h; bd.hb[3] = hb2h; bd.dim[3] = 256;
    bd.b[4] = b3b; bd.hb[4] = hb3b; bd.dim[4] = 128;
    bd.b[5] = b3h; bd.hb[5] = hb3h; bd.dim[5] = 128;
    bias_all_k<<<6, 64, 0, stream>>>(bd, hbsq);
  }
  {
    WsDesc wd;
    wd.src[0] = W1b; wd.dst[0] = wb1b; wd.K[0] = 256; wd.total[0] = 8 * 8 * 64;
    wd.src[1] = W1h; wd.dst[1] = wb1h; wd.K[1] = 256; wd.total[1] = 8 * 8 * 64;
    wd.src[2] = W2b; wd.dst[2] = wb2b; wd.K[2] = 384; wd.total[2] = 16 * 12 * 64;
    wd.src[3] = W2h; wd.dst[3] = wb2h; wd.K[3] = 384; wd.total[3] = 16 * 12 * 64;
    wd.src[4] = W3b; wd.dst[4] = wb3b; wd.K[4] = 256; wd.total[4] = 8 * 8 * 64;
    wd.src[5] = W3h; wd.dst[5] = wb3h; wd.K[5] = 256; wd.total[5] = 8 * 8 * 64;
    wshuf_all_k<<<dim3(48, 6), 256, 0, stream>>>(wd);
  }

  // ---- layer 1 aggs: A_P(x)->TD, A_N(x)->TE ----
  {
    AggJob jp{TA, 128, 0, 0, cur_p, lst_p, TD, nullptr, ssq_p1, nullptr};
    AggJob jn{TA, 128, 0, 0, cur_n, lst_n, TE, nullptr, ssq_n1, nullptr};
    agg2_k<1><<<dim3(grow, 2), 256, 0, stream>>>(jp, jn, N);
  }
  // ---- layer 1 gemms: write hb1|hn1 interleaved into H1 ----
  {
    GJob ja{}, jh{};
    ja.p[0] = TD; ja.lda[0] = 128; ja.ko[0] = 0;
    ja.p[1] = TA; ja.lda[1] = 128; ja.ko[1] = 0;
    ja.Wp = wb1b; ja.xs0 = ssq_p1; ja.xs1 = xsq; ja.xs2 = nullptr;
    ja.hb = hb1b; ja.hbsq_p = hbsq + 0;
    ja.ob0 = H1; ja.ob1 = nullptr; ja.ldob = 256;
    ja.outf = nullptr; ja.ldof = 0; ja.ocol = 0; ja.hsq_out = hsq_b1;
    jh = ja;
    jh.p[0] = TE; jh.Wp = wb1h; jh.xs0 = ssq_n1;
    jh.hb = hb1h; jh.hbsq_p = hbsq + 1; jh.ob0 = H1 + 128; jh.hsq_out = hsq_n1;
    gemm3_k<2, 2><<<dim3(gf, 2), 256, 0, stream>>>(ja, jh, N);
  }

  // ---- layer 2 aggs over interleaved H1 (ofs 0 = hb1, ofs 128 = hn1) ----
  {
    // P job: O0 = A_P(hb1)=TD, O1 = A_P(hn1)=TE
    AggJob jp{H1, 256, 0, 128, cur_p, lst_p, TD, TE, ssq_pp, ssq_np};
    // N job: O0 = A_N(hn1)=TA, O1 = A_N(hb1)=TF
    AggJob jn{H1, 256, 128, 0, cur_n, lst_n, TA, TF, ssq_nn, ssq_bn};
    agg2_k<2><<<dim3(grow, 2), 256, 0, stream>>>(jp, jn, N);
  }
  // ---- layer 2 gemms: HB2 -> [TD|TA], HN2 -> [TE|TF] (alias inputs, row-aligned) ----
  {
    GJob ja{}, jh{};
    ja.p[0] = TD; ja.lda[0] = 128; ja.ko[0] = 0;
    ja.p[1] = TA; ja.lda[1] = 128; ja.ko[1] = 0;
    ja.p[2] = H1; ja.lda[2] = 256; ja.ko[2] = 0;
    ja.Wp = wb2b; ja.xs0 = ssq_pp; ja.xs1 = ssq_nn; ja.xs2 = hsq_b1;
    ja.hb = hb2b; ja.hbsq_p = hbsq + 2;
    ja.ob0 = TD; ja.ob1 = TA; ja.ldob = 128;
    ja.outf = nullptr; ja.ldof = 0; ja.ocol = 0; ja.hsq_out = hsq_b2;
    jh = ja;
    jh.p[0] = TE; jh.p[1] = TF; jh.ko[2] = 128;
    jh.Wp = wb2h; jh.xs0 = ssq_np; jh.xs1 = ssq_bn; jh.xs2 = hsq_n1;
    jh.hb = hb2h; jh.hbsq_p = hbsq + 3;
    jh.ob0 = TE; jh.ob1 = TF; jh.hsq_out = hsq_n2;
    gemm3_k<3, 4><<<dim3(gf, 2), 256, 0, stream>>>(ja, jh, N);
  }

  // ---- layer 3: hb2=[TD|TA] -> out[:,0:128]; hn2=[TE|TF] -> out[:,128:256] ----
  {
    GJob ja{}, jh{};
    ja.p[0] = TD; ja.lda[0] = 128; ja.ko[0] = 0;
    ja.p[1] = TA; ja.lda[1] = 128; ja.ko[1] = 0;
    ja.Wp = wb3b; ja.xs0 = hsq_b2; ja.xs1 = nullptr; ja.xs2 = nullptr;
    ja.hb = hb3b; ja.hbsq_p = hbsq + 4;
    ja.ob0 = nullptr; ja.ob1 = nullptr; ja.ldob = 0;
    ja.outf = outf; ja.ldof = 3 * D; ja.ocol = 0; ja.hsq_out = nullptr;
    jh = ja;
    jh.p[0] = TE; jh.p[1] = TF;
    jh.Wp = wb3h; jh.xs0 = hsq_n2;
    jh.hb = hb3h; jh.hbsq_p = hbsq + 5; jh.ocol = 128;
    gemm3_k<2, 2><<<dim3(gf, 2), 256, 0, stream>>>(ja, jh, N);
  }
}